// Round 11
// baseline (168.076 us; speedup 1.0000x reference)
//
#include <hip/hip_runtime.h>
#include <hip/hip_bf16.h>

#define B_ 8
#define S_ 1024
#define D_ 1024
#define H_ 16
#define HD_ 64
#define M_ (B_*S_)
#define NQB (S_/128)

typedef __attribute__((ext_vector_type(8))) short short8;
typedef __attribute__((ext_vector_type(4))) short short4v;
typedef __attribute__((ext_vector_type(4))) float f32x4;
typedef __attribute__((ext_vector_type(16))) float f32x16;
typedef __attribute__((ext_vector_type(4))) int int4v;
typedef __attribute__((ext_vector_type(2))) int int2v;

#define CSC 0.18033688f   // 0.125 * log2(e)

__device__ __forceinline__ unsigned short f2bf(float f) {
    unsigned int u = __float_as_uint(f);
    u += 0x7FFF + ((u >> 16) & 1);          // round-to-nearest-even
    return (unsigned short)(u >> 16);
}

__device__ __forceinline__ void gload16(const void* g, void* l) {
    __builtin_amdgcn_global_load_lds(
        (const __attribute__((address_space(1))) void*)g,
        (__attribute__((address_space(3))) void*)l, 16, 0, 0);
}

__device__ __forceinline__ int2v plswap(int a, int b) {
    return __builtin_amdgcn_permlane32_swap(a, b, false, false);
}

__device__ __forceinline__ float max3f(float a, float b, float c) {
    return fmaxf(fmaxf(a, b), c);
}

// ---------------------------------------------------------------------------
// f32 -> bf16 conversion, weights only (4 segments of 1M elements)
// ---------------------------------------------------------------------------
struct CvtSeg { const float* src; unsigned short* dst; };
struct CvtArgs { CvtSeg s[4]; };

__global__ __launch_bounds__(256)
void cvt_w(CvtArgs a)
{
    const CvtSeg seg = a.s[blockIdx.y];
    int i = blockIdx.x * 256 + threadIdx.x;          // 512 blocks x 256 = n8
    float4 x = reinterpret_cast<const float4*>(seg.src)[i*2];
    float4 y = reinterpret_cast<const float4*>(seg.src)[i*2+1];
    short8 v = short8{(short)f2bf(x.x),(short)f2bf(x.y),(short)f2bf(x.z),(short)f2bf(x.w),
                      (short)f2bf(y.x),(short)f2bf(y.y),(short)f2bf(y.z),(short)f2bf(y.w)};
    reinterpret_cast<short8*>(seg.dst)[i] = v;
}

// ---------------------------------------------------------------------------
// Projection GEMM core (r7 PROVEN BEST): A is f32 (reg-staged, converted
// in-flight, swizzled ds_write); B is bf16 (global_load_lds, inverse-swizzled
// source).  Depth-2 A-register pipeline (ar0/ar1 ping-pong, LOADA(t+2) at
// iter t); end-of-iter counted vmcnt(8) drains A(t+1)+B(t+1), leaves A(t+2)
// in flight across the barrier.  x2 unroll for static reg-set indexing.
// BM=BN=128, BK=64, 4 waves, 64KB dbuf LDS, 1 barrier/iter.
// ---------------------------------------------------------------------------
__device__ __forceinline__ void gemm_core_f32A(
    const float* __restrict__ A, const unsigned short* __restrict__ Wb,
    short* lds, int m0, int n0, int tid, f32x4 (&acc)[4][4])
{
    const int K = D_;
    const int lane = tid & 63, wave = tid >> 6;
    const int wr = wave >> 1, wc = wave & 1;
    const int r16 = lane & 15, g4 = lane >> 4;
    const int sr8  = lane >> 3;                      // 0..7 row-in-chunk
    const int slot = lane & 7;
    const int scol = ((lane ^ sr8) & 7) * 8;         // inverse-swizzled B src col
    const int wsl  = (slot ^ sr8) << 3;              // swizzled A LDS slot (shorts)

    float4 ar0[4][2], ar1[4][2];                     // two A reg sets (ping-pong)

    #define STAGEB(t, bi)                                                     \
        { _Pragma("unroll")                                                   \
          for (int c = 0; c < 4; ++c) {                                       \
              int chunk = wave*4 + c;                                         \
              gload16(Wb + (size_t)(n0 + chunk*8 + sr8) * K + (t)*64 + scol,  \
                      lds + (bi)*16384 + 8192 + chunk*512);                   \
          } }

    #define LOADA_S(t, AR)                                                    \
        { _Pragma("unroll")                                                   \
          for (int c = 0; c < 4; ++c) {                                       \
              const float* src = A + (size_t)(m0 + wave*32 + c*8 + sr8)*K     \
                                   + (t)*64 + slot*8;                         \
              AR[c][0] = *reinterpret_cast<const float4*>(src);               \
              AR[c][1] = *reinterpret_cast<const float4*>(src + 4);           \
          } }

    #define WRITEA_S(bi, AR)                                                  \
        { _Pragma("unroll")                                                   \
          for (int c = 0; c < 4; ++c) {                                       \
              unsigned w0, w1, w2, w3;                                        \
              asm("v_cvt_pk_bf16_f32 %0, %1, %2" : "=v"(w0) : "v"(AR[c][0].x), "v"(AR[c][0].y)); \
              asm("v_cvt_pk_bf16_f32 %0, %1, %2" : "=v"(w1) : "v"(AR[c][0].z), "v"(AR[c][0].w)); \
              asm("v_cvt_pk_bf16_f32 %0, %1, %2" : "=v"(w2) : "v"(AR[c][1].x), "v"(AR[c][1].y)); \
              asm("v_cvt_pk_bf16_f32 %0, %1, %2" : "=v"(w3) : "v"(AR[c][1].z), "v"(AR[c][1].w)); \
              int4v wi; wi.x = (int)w0; wi.y = (int)w1; wi.z = (int)w2; wi.w = (int)w3; \
              *reinterpret_cast<int4v*>(                                      \
                  &lds[(bi)*16384 + (wave*32 + c*8 + sr8)*64 + wsl]) = wi;    \
          } }

    const int NT = K / 64;                           // 16, even

    // prologue: B(0)+A(0) -> buf0; A(1) left in flight in ar1
    STAGEB(0, 0);
    LOADA_S(0, ar0);
    asm volatile("s_waitcnt vmcnt(0)" ::: "memory");
    WRITEA_S(0, ar0);
    LOADA_S(1, ar1);
    asm volatile("s_waitcnt lgkmcnt(0)" ::: "memory");
    __builtin_amdgcn_s_barrier();

    #define ITER(t, cur, ARCUR, AROTH)                                        \
    {                                                                         \
        if ((t) + 1 < NT) STAGEB((t)+1, (cur)^1);                             \
        if ((t) + 2 < NT) LOADA_S((t)+2, ARCUR);                              \
        const short* Ab = lds + (cur)*16384;                                  \
        const short* Bb = Ab + 8192;                                          \
        _Pragma("unroll")                                                     \
        for (int ks = 0; ks < 2; ++ks) {                                      \
            short8 af[4], bf[4];                                              \
            _Pragma("unroll")                                                 \
            for (int m = 0; m < 4; ++m) {                                     \
                int r = wr*64 + m*16 + r16;                                   \
                af[m] = *reinterpret_cast<const short8*>(                     \
                    &Ab[r*64 + (((ks*4 + g4) ^ (r16 & 7)) << 3)]);            \
            }                                                                 \
            _Pragma("unroll")                                                 \
            for (int n = 0; n < 4; ++n) {                                     \
                int r = wc*64 + n*16 + r16;                                   \
                bf[n] = *reinterpret_cast<const short8*>(                     \
                    &Bb[r*64 + (((ks*4 + g4) ^ (r16 & 7)) << 3)]);            \
            }                                                                 \
            __builtin_amdgcn_s_setprio(1);                                    \
            _Pragma("unroll")                                                 \
            for (int m = 0; m < 4; ++m)                                       \
                _Pragma("unroll")                                             \
                for (int n = 0; n < 4; ++n)                                   \
                    acc[m][n] = __builtin_amdgcn_mfma_f32_16x16x32_bf16(af[m], bf[n], acc[m][n], 0, 0, 0); \
            __builtin_amdgcn_s_setprio(0);                                    \
        }                                                                     \
        if ((t) + 1 < NT) {                                                   \
            if ((t) + 2 < NT) asm volatile("s_waitcnt vmcnt(8)" ::: "memory");\
            else              asm volatile("s_waitcnt vmcnt(0)" ::: "memory");\
            WRITEA_S((cur)^1, AROTH);                                         \
            asm volatile("s_waitcnt lgkmcnt(0)" ::: "memory");                \
        }                                                                     \
        __builtin_amdgcn_s_barrier();                                         \
    }

    for (int t = 0; t < NT; t += 2) {
        ITER(t,     0, ar0, ar1);
        ITER(t + 1, 1, ar1, ar0);
    }
    #undef ITER
    #undef STAGEB
    #undef LOADA_S
    #undef WRITEA_S
}

// ---------------------------------------------------------------------------
// bf16-A GEMM core (final GEMM): proven structure — dual gload_lds,
// counted vmcnt(8), 2 raw barriers/iter.
// ---------------------------------------------------------------------------
__device__ __forceinline__ void gemm_core_bf16A(
    const unsigned short* __restrict__ A, const unsigned short* __restrict__ Wb,
    short* lds, int m0, int n0, int tid, f32x4 (&acc)[4][4])
{
    const int K = D_;
    const int lane = tid & 63, wave = tid >> 6;
    const int wr = wave >> 1, wc = wave & 1;
    const int r16 = lane & 15, g4 = lane >> 4;
    const int srow = lane >> 3;
    const int scol = ((lane ^ srow) & 7) * 8;

    #define STAGE(t, bi)                                                      \
        { _Pragma("unroll")                                                   \
          for (int c = 0; c < 4; ++c) {                                       \
              int chunk = wave*4 + c;                                         \
              gload16(Wb + (size_t)(n0 + chunk*8 + srow) * K + (t)*64 + scol, \
                      lds + (bi)*16384 + 8192 + chunk*512);                   \
              gload16(A + (size_t)(m0 + chunk*8 + srow) * K + (t)*64 + scol,  \
                      lds + (bi)*16384 + chunk*512);                          \
          } }

    STAGE(0, 0);

    const int NT = K / 64;
    for (int t = 0; t < NT; ++t) {
        const int cur = t & 1;
        if (t + 1 < NT) {
            STAGE(t+1, cur^1);
            asm volatile("s_waitcnt vmcnt(8)" ::: "memory");
        } else {
            asm volatile("s_waitcnt vmcnt(0)" ::: "memory");
        }
        __builtin_amdgcn_s_barrier();

        const short* Ab = lds + cur*16384;
        const short* Bb = Ab + 8192;
        #pragma unroll
        for (int ks = 0; ks < 2; ++ks) {
            short8 af[4], bf[4];
            #pragma unroll
            for (int m = 0; m < 4; ++m) {
                int r = wr*64 + m*16 + r16;
                af[m] = *reinterpret_cast<const short8*>(
                    &Ab[r*64 + (((ks*4 + g4) ^ (r16 & 7)) << 3)]);
            }
            #pragma unroll
            for (int n = 0; n < 4; ++n) {
                int r = wc*64 + n*16 + r16;
                bf[n] = *reinterpret_cast<const short8*>(
                    &Bb[r*64 + (((ks*4 + g4) ^ (r16 & 7)) << 3)]);
            }
            __builtin_amdgcn_s_setprio(1);
            #pragma unroll
            for (int m = 0; m < 4; ++m)
                #pragma unroll
                for (int n = 0; n < 4; ++n)
                    acc[m][n] = __builtin_amdgcn_mfma_f32_16x16x32_bf16(af[m], bf[n], acc[m][n], 0, 0, 0);
            __builtin_amdgcn_s_setprio(0);
        }
        __builtin_amdgcn_s_barrier();
    }
    #undef STAGE
}

// Vectorized epilogue via padded LDS scratch [64][132] f32 (conflict-free),
// 2 passes of 64 rows.  MODE: 0 bf16, 1 f32, 3 bf16 scaled by CSC
template<int MODE>
__device__ __forceinline__ void epilogue_vec(
    float* Cl, void* __restrict__ Ov, int m0, int n0, int tid, f32x4 (&acc)[4][4])
{
    const int N = D_;
    const int lane = tid & 63, wave = tid >> 6;
    const int wr = wave >> 1, wc = wave & 1;
    const int r16 = lane & 15, g4 = lane >> 4;

    #pragma unroll
    for (int p = 0; p < 2; ++p) {
        if (p) __syncthreads();
        if (wr == p) {
            #pragma unroll
            for (int m = 0; m < 4; ++m)
                #pragma unroll
                for (int n = 0; n < 4; ++n)
                    #pragma unroll
                    for (int i = 0; i < 4; ++i)
                        Cl[(m*16 + g4*4 + i)*132 + wc*64 + n*16 + r16] = acc[m][n][i];
        }
        __syncthreads();
        if (MODE == 1) {
            #pragma unroll
            for (int j = 0; j < 8; ++j) {
                int c = j*256 + tid;
                int row = c >> 5, cg = c & 31;
                float4 val = *reinterpret_cast<const float4*>(&Cl[row*132 + cg*4]);
                *reinterpret_cast<float4*>(
                    &((float*)Ov)[(size_t)(m0 + p*64 + row)*N + n0 + cg*4]) = val;
            }
        } else {
            #pragma unroll
            for (int j = 0; j < 4; ++j) {
                int c2 = j*256 + tid;
                int row = c2 >> 4, col = (c2 & 15)*8;
                float4 a = *reinterpret_cast<const float4*>(&Cl[row*132 + col]);
                float4 bq = *reinterpret_cast<const float4*>(&Cl[row*132 + col + 4]);
                if (MODE == 3) {
                    a.x *= CSC; a.y *= CSC; a.z *= CSC; a.w *= CSC;
                    bq.x *= CSC; bq.y *= CSC; bq.z *= CSC; bq.w *= CSC;
                }
                short8 v = short8{(short)f2bf(a.x),(short)f2bf(a.y),(short)f2bf(a.z),(short)f2bf(a.w),
                                  (short)f2bf(bq.x),(short)f2bf(bq.y),(short)f2bf(bq.z),(short)f2bf(bq.w)};
                *reinterpret_cast<short8*>(
                    &((unsigned short*)Ov)[(size_t)(m0 + p*64 + row)*N + n0 + col]) = v;
            }
        }
    }
}

// ---------------------------------------------------------------------------
// Merged projection GEMMs: grid 1536 = 3 x 512, XCD-chunked within each 512.
// L2-reuse mapping (r6-proven): 8 temporally-adjacent blocks on an XCD share
// ONE A m-tile and sweep all 8 n-tiles; full W (2MB bf16) L2-resident.
// which: 0 = Q (bf16 out, pre-scaled CSC), 1 = K (bf16), 2 = V (transposed).
// ---------------------------------------------------------------------------
struct ProjArgs {
    const float* A[3];
    const unsigned short* W[3];
    void* O[3];
};

__global__ __launch_bounds__(256)
void gemm_proj(ProjArgs pa)
{
    __shared__ __align__(16) short lds[32768];       // 64 KB

    const int L = blockIdx.x;
    const int which = L >> 9;
    const int inner = L & 511;
    const int xcd = inner & 7, jj = inner >> 3;      // same-xcd blocks: consecutive jj
    const int m0 = (xcd*8 + (jj >> 3)) * 128;        // 8 m-tiles per XCD, held 8 blocks
    const int n0 = (jj & 7) * 128;                   // consecutive blocks sweep n
    const int tid = threadIdx.x;

    f32x4 acc[4][4] = {};
    gemm_core_f32A(pa.A[which], pa.W[which], lds, m0, n0, tid, acc);

    if (which == 2) {
        // transposed epilogue: VtG[((b*16+h)*64 + d)][s]
        const int lane = tid & 63, wave = tid >> 6;
        const int wr = wave >> 1, wc = wave & 1;
        const int r16 = lane & 15, g4 = lane >> 4;
        #pragma unroll
        for (int m = 0; m < 4; ++m) {
            int row0 = m0 + wr*64 + m*16 + g4*4;
            #pragma unroll
            for (int n = 0; n < 4; ++n) {
                int col = n0 + wc*64 + n*16 + r16;
                size_t vrow = (size_t)((row0 >> 10)*16 + (col >> 6))*64 + (col & 63);
                short4v pk = short4v{(short)f2bf(acc[m][n][0]), (short)f2bf(acc[m][n][1]),
                                     (short)f2bf(acc[m][n][2]), (short)f2bf(acc[m][n][3])};
                *reinterpret_cast<short4v*>((unsigned short*)pa.O[2] + vrow*S_ + (row0 & 1023)) = pk;
            }
        }
    } else if (which == 0) {
        epilogue_vec<3>((float*)lds, pa.O[0], m0, n0, tid, acc);
    } else {
        epilogue_vec<0>((float*)lds, pa.O[1], m0, n0, tid, acc);
    }
}

// ---------------------------------------------------------------------------
// Final GEMM (AO @ Wo.T -> f32), 512 blocks, same L2-reuse mapping.
// ---------------------------------------------------------------------------
__global__ __launch_bounds__(256)
void gemm_final(const unsigned short* __restrict__ A, const unsigned short* __restrict__ Wb,
                float* __restrict__ Ov)
{
    __shared__ __align__(16) short lds[32768];

    const int L = blockIdx.x;
    const int xcd = L & 7, jj = L >> 3;
    const int m0 = (xcd*8 + (jj >> 3)) * 128;
    const int n0 = (jj & 7) * 128;
    const int tid = threadIdx.x;

    f32x4 acc[4][4] = {};
    gemm_core_bf16A(A, Wb, lds, m0, n0, tid, acc);
    epilogue_vec<1>((float*)lds, Ov, m0, n0, tid, acc);
}

// ---------------------------------------------------------------------------
// Flash attention (causal), swapped-operand 32x32 MFMA, causal-paired tiles.
// KVBLK=128 — one barrier per PAIR of 64-row windows.  Windows A/B of a pair
// are independent until the o-accumulate: QK^T(B) is issued BEFORE
// softmax(A), so B's MFMA latency hides under A's serial softmax chain, and
// softmax(B) hides under PV(A).  Barriers halve (18->10).
// K/V staged via global_load_lds (linear dest + inverse-swizzled source).
// LDS 64KB (2buf x 2win x (K 8KB + V 8KB)); grid 512 = 2 blocks/CU.
// Q pre-scaled by CSC (exp2 domain); permlane32_swap cross-half exchange.
// NOTE: macro params must avoid 'w' (collides with .w member access — r10).
// ---------------------------------------------------------------------------
__global__ __launch_bounds__(256)
void attn_fwd(const unsigned short* __restrict__ Qh,
              const unsigned short* __restrict__ Kh,
              const unsigned short* __restrict__ VtG,
              unsigned short* __restrict__ AO)
{
    __shared__ __align__(16) short Kl[2][2][64*64];
    __shared__ __align__(16) short Vl[2][2][64*64];

    const int tid  = threadIdx.x;
    const int lane = tid & 63, wave = tid >> 6;
    const int l31 = lane & 31, h32 = lane >> 5;
    const int L = blockIdx.x;
    const int xcd = L & 7, jj = L >> 3;
    const int pr = jj & 3;
    const int hb = xcd*16 + (jj >> 2);
    const int h = hb & 15, b = hb >> 4;

    const int slot = tid & 7;
    const int r0 = tid >> 3, r1 = r0 + 32;           // rows 0..31 / 32..63
    const int sc8 = ((slot ^ (r0 & 7)) << 3);        // inverse-swizzled src col

    const unsigned short* Kg0 = Kh + ((size_t)b*S_)*D_ + h*HD_;
    const unsigned short* Vg0 = VtG + ((size_t)(b*H_ + h)*HD_)*S_;

    // stage pair j1 (128 K-rows / 128 V-cols) into buffer nb
    #define STAGEKV128(j1, nb)                                                \
        { const unsigned short* Kg = Kg0 + (size_t)(j1)*128*D_;               \
          const unsigned short* Vg = Vg0 + (size_t)(j1)*128;                  \
          gload16(Kg + (size_t)r0*D_ + sc8,      &Kl[nb][0][r0*64 + slot*8]); \
          gload16(Kg + (size_t)r1*D_ + sc8,      &Kl[nb][0][r1*64 + slot*8]); \
          gload16(Kg + (size_t)(r0+64)*D_ + sc8, &Kl[nb][1][r0*64 + slot*8]); \
          gload16(Kg + (size_t)(r1+64)*D_ + sc8, &Kl[nb][1][r1*64 + slot*8]); \
          gload16(Vg + (size_t)r0*S_ + sc8,      &Vl[nb][0][r0*64 + slot*8]); \
          gload16(Vg + (size_t)r1*S_ + sc8,      &Vl[nb][0][r1*64 + slot*8]); \
          gload16(Vg + 64 + (size_t)r0*S_ + sc8, &Vl[nb][1][r0*64 + slot*8]); \
          gload16(Vg + 64 + (size_t)r1*S_ + sc8, &Vl[nb][1][r1*64 + slot*8]); }

    #define QKT_W(cur, vw, p0, p1)                                            \
        { __builtin_amdgcn_s_setprio(1);                                      \
          _Pragma("unroll")                                                   \
          for (int m = 0; m < 4; ++m) {                                       \
              short8 kf0 = *reinterpret_cast<const short8*>(                  \
                  &Kl[cur][vw][l31*64 + ((((m<<1)|h32) ^ (l31 & 7)) << 3)]);  \
              short8 kf1 = *reinterpret_cast<const short8*>(                  \
                  &Kl[cur][vw][(32 + l31)*64 + ((((m<<1)|h32) ^ (l31 & 7)) << 3)]); \
              p0 = __builtin_amdgcn_mfma_f32_32x32x16_bf16(kf0, qf[m], p0, 0, 0, 0); \
              p1 = __builtin_amdgcn_mfma_f32_32x32x16_bf16(kf1, qf[m], p1, 0, 0, 0); \
          }                                                                   \
          __builtin_amdgcn_s_setprio(0); }

    #define MASK_W(kb, p0, p1)                                                \
        if ((kb)*64 + 63 > q0w) {                                             \
            _Pragma("unroll")                                                 \
            for (int r = 0; r < 16; ++r) {                                    \
                int kk = (r & 3) + ((r >> 2) << 3) + (h32 << 2);              \
                if ((kb)*64      + kk > qi) p0[r] = -1e30f;                   \
                if ((kb)*64 + 32 + kk > qi) p1[r] = -1e30f;                   \
            } }

    #define SOFTMAX_W(p0, p1) {                                               \
        float t0 = max3f(p0[0],  p0[1],  p0[2]);                              \
        float t1 = max3f(p0[3],  p0[4],  p0[5]);                              \
        float t2 = max3f(p0[6],  p0[7],  p0[8]);                              \
        float t3 = max3f(p0[9],  p0[10], p0[11]);                             \
        float t4 = max3f(p0[12], p0[13], p0[14]);                             \
        float t5 = max3f(p0[15], p1[0],  p1[1]);                              \
        float t6 = max3f(p1[2],  p1[3],  p1[4]);                              \
        float t7 = max3f(p1[5],  p1[6],  p1[7]);                              \
        float t8 = max3f(p1[8],  p1[9],  p1[10]);                             \
        float t9 = max3f(p1[11], p1[12], p1[13]);                             \
        float ta = fmaxf(p1[14], p1[15]);                                     \
        float mloc = fmaxf(max3f(max3f(t0,t1,t2), max3f(t3,t4,t5),            \
                                 max3f(t6,t7,t8)), fmaxf(t9, ta));            \
        int2v mm = plswap(__float_as_int(mloc), __float_as_int(mloc));        \
        float pm = fmaxf(__int_as_float(mm.x), __int_as_float(mm.y));         \
        if (__any(pm > mrow + 11.5416f)) {                                    \
            float mn = fmaxf(mrow, pm);                                       \
            float so = exp2f(mrow - mn);                                      \
            _Pragma("unroll")                                                 \
            for (int r = 0; r < 16; ++r) { o0[r] *= so; o1[r] *= so; }        \
            lsum *= so;                                                       \
            mrow = mn;                                                        \
        }                                                                     \
        _Pragma("unroll")                                                     \
        for (int r = 0; r < 16; ++r) p0[r] = exp2f(p0[r] - mrow);             \
        _Pragma("unroll")                                                     \
        for (int r = 0; r < 16; ++r) p1[r] = exp2f(p1[r] - mrow);             \
        float sq[8];                                                          \
        _Pragma("unroll")                                                     \
        for (int r = 0; r < 8; ++r)                                           \
            sq[r] = (p0[2*r] + p0[2*r+1]) + (p1[2*r] + p1[2*r+1]);            \
        float rs = ((sq[0]+sq[1]) + (sq[2]+sq[3])) + ((sq[4]+sq[5]) + (sq[6]+sq[7])); \
        int2v ss = plswap(__float_as_int(rs), __float_as_int(rs));            \
        lsum += __int_as_float(ss.x) + __int_as_float(ss.y); }

    #define PV_W(cur, vw, p0, p1)                                             \
        { _Pragma("unroll")                                                   \
          for (int m = 0; m < 4; ++m) {                                       \
              const int mb = (m & 1) * 8;                                     \
              unsigned int C0, C1, C2, C3;                                    \
              if (m < 2) {                                                    \
                  asm("v_cvt_pk_bf16_f32 %0, %1, %2" : "=v"(C0) : "v"(p0[mb+0]), "v"(p0[mb+1])); \
                  asm("v_cvt_pk_bf16_f32 %0, %1, %2" : "=v"(C1) : "v"(p0[mb+2]), "v"(p0[mb+3])); \
                  asm("v_cvt_pk_bf16_f32 %0, %1, %2" : "=v"(C2) : "v"(p0[mb+4]), "v"(p0[mb+5])); \
                  asm("v_cvt_pk_bf16_f32 %0, %1, %2" : "=v"(C3) : "v"(p0[mb+6]), "v"(p0[mb+7])); \
              } else {                                                        \
                  asm("v_cvt_pk_bf16_f32 %0, %1, %2" : "=v"(C0) : "v"(p1[mb+0]), "v"(p1[mb+1])); \
                  asm("v_cvt_pk_bf16_f32 %0, %1, %2" : "=v"(C1) : "v"(p1[mb+2]), "v"(p1[mb+3])); \
                  asm("v_cvt_pk_bf16_f32 %0, %1, %2" : "=v"(C2) : "v"(p1[mb+4]), "v"(p1[mb+5])); \
                  asm("v_cvt_pk_bf16_f32 %0, %1, %2" : "=v"(C3) : "v"(p1[mb+6]), "v"(p1[mb+7])); \
              }                                                               \
              int2v s0 = plswap((int)C0, (int)C2);                            \
              int2v s1 = plswap((int)C1, (int)C3);                            \
              int4v wi; wi.x = s0.x; wi.y = s1.x; wi.z = s0.y; wi.w = s1.y;   \
              short8 pf = __builtin_bit_cast(short8, wi);                     \
              short8 vf0 = *reinterpret_cast<const short8*>(                  \
                  &Vl[cur][vw][l31*64 + ((((m<<1)|h32) ^ (l31 & 7)) << 3)]);  \
              short8 vf1 = *reinterpret_cast<const short8*>(                  \
                  &Vl[cur][vw][(32 + l31)*64 + ((((m<<1)|h32) ^ (l31 & 7)) << 3)]); \
              o0 = __builtin_amdgcn_mfma_f32_32x32x16_bf16(vf0, pf, o0, 0, 0, 0); \
              o1 = __builtin_amdgcn_mfma_f32_32x32x16_bf16(vf1, pf, o1, 0, 0, 0); \
          } }

    for (int t = 0; t < 2; ++t) {
        const int qb = t ? pr : (NQB - 1 - pr);
        const int q0w = qb*128 + wave*32;
        const int qi  = q0w + l31;

        short8 qf[4];
        #pragma unroll
        for (int m = 0; m < 4; ++m)
            qf[m] = *reinterpret_cast<const short8*>(
                Qh + ((size_t)b*S_ + qi)*D_ + h*HD_ + m*16 + h32*8);

        f32x16 o0 = {}, o1 = {};
        float mrow = -1e30f, lsum = 0.f;
        const int np = qb + 1;                       // pairs of 64-row windows

        STAGEKV128(0, 0);
        asm volatile("s_waitcnt vmcnt(0)" ::: "memory");
        __syncthreads();

        for (int j = 0; j < np; ++j) {
            const int cur = j & 1;
            if (j + 1 < np) STAGEKV128(j+1, cur^1);

            const int kbA = 2*j, kbB = 2*j + 1;
            // window A (rows 2j*64..) is active for ALL waves (2j*64 <= q0w);
            // only window B may be masked-out for waves 0/1 in the last pair.
            const bool actB = (kbB*64 <= q0w + 31);

            f32x16 pA0 = {}, pA1 = {}, pB0 = {}, pB1 = {};
            QKT_W(cur, 0, pA0, pA1);
            if (actB) QKT_W(cur, 1, pB0, pB1);       // hides under softmax(A)

            MASK_W(kbA, pA0, pA1);
            SOFTMAX_W(pA0, pA1);
            PV_W(cur, 0, pA0, pA1);

            if (actB) {
                MASK_W(kbB, pB0, pB1);
                SOFTMAX_W(pB0, pB1);
                PV_W(cur, 1, pB0, pB1);
            }

            asm volatile("s_waitcnt vmcnt(0)" ::: "memory");
            __syncthreads();
        }

        float inv = 1.f / lsum;
        #pragma unroll
        for (int tt = 0; tt < 2; ++tt) {
            #pragma unroll
            for (int g = 0; g < 4; ++g) {
                short4v pk;
                #pragma unroll
                for (int j2 = 0; j2 < 4; ++j2) {
                    float val = (tt ? o1[g*4+j2] : o0[g*4+j2]) * inv;
                    pk[j2] = (short)f2bf(val);
                }
                int d = tt*32 + g*8 + h32*4;
                *reinterpret_cast<short4v*>(AO + ((size_t)b*S_ + qi)*D_ + h*HD_ + d) = pk;
            }
        }
    }
    #undef STAGEKV128
    #undef QKT_W
    #undef MASK_W
    #undef SOFTMAX_W
    #undef PV_W
}

// ---------------------------------------------------------------------------
extern "C" void kernel_launch(void* const* d_in, const int* in_sizes, int n_in,
                              void* d_out, int out_size, void* d_ws, size_t ws_size,
                              hipStream_t stream) {
    const float* q  = (const float*)d_in[0];
    const float* k  = (const float*)d_in[1];
    const float* v  = (const float*)d_in[2];
    const float* Wq = (const float*)d_in[3];
    const float* Wk = (const float*)d_in[4];
    const float* Wv = (const float*)d_in[5];
    const float* Wo = (const float*)d_in[6];

    unsigned short* Wqb = (unsigned short*)d_ws;            // 4 x 2MB bf16
    unsigned short* Wkb = Wqb + (size_t)D_*D_;
    unsigned short* Wvb = Wkb + (size_t)D_*D_;
    unsigned short* Wob = Wvb + (size_t)D_*D_;
    unsigned short* Qh  = Wob + (size_t)D_*D_;              // projected, bf16
    unsigned short* Kh  = Qh  + (size_t)M_*D_;
    unsigned short* VtG = Kh  + (size_t)M_*D_;              // [(b,h,d), s]
    unsigned short* AO  = VtG + (size_t)M_*D_;              // attention out

    dim3 blk(256);
    CvtArgs ca;
    ca.s[0] = CvtSeg{Wq, Wqb};
    ca.s[1] = CvtSeg{Wk, Wkb};
    ca.s[2] = CvtSeg{Wv, Wvb};
    ca.s[3] = CvtSeg{Wo, Wob};
    cvt_w<<<dim3(512, 4), blk, 0, stream>>>(ca);

    ProjArgs pa;
    pa.A[0] = q;  pa.W[0] = Wqb; pa.O[0] = Qh;
    pa.A[1] = k;  pa.W[1] = Wkb; pa.O[1] = Kh;
    pa.A[2] = v;  pa.W[2] = Wvb; pa.O[2] = VtG;
    gemm_proj<<<dim3(1536), blk, 0, stream>>>(pa);

    attn_fwd<<<dim3(512), blk, 0, stream>>>(Qh, Kh, VtG, AO);

    gemm_final<<<dim3(512), blk, 0, stream>>>(AO, Wob, (float*)d_out);
}

// Round 12
// 150.218 us; speedup vs baseline: 1.1189x; 1.1189x over previous
//
#include <hip/hip_runtime.h>
#include <hip/hip_bf16.h>

#define B_ 8
#define S_ 1024
#define D_ 1024
#define H_ 16
#define HD_ 64
#define M_ (B_*S_)
#define NQB (S_/128)

typedef __attribute__((ext_vector_type(8))) short short8;
typedef __attribute__((ext_vector_type(4))) short short4v;
typedef __attribute__((ext_vector_type(4))) float f32x4;
typedef __attribute__((ext_vector_type(16))) float f32x16;
typedef __attribute__((ext_vector_type(4))) int int4v;
typedef __attribute__((ext_vector_type(2))) int int2v;

#define CSC 0.18033688f   // 0.125 * log2(e)

__device__ __forceinline__ unsigned short f2bf(float f) {
    unsigned int u = __float_as_uint(f);
    u += 0x7FFF + ((u >> 16) & 1);          // round-to-nearest-even
    return (unsigned short)(u >> 16);
}

__device__ __forceinline__ void gload16(const void* g, void* l) {
    __builtin_amdgcn_global_load_lds(
        (const __attribute__((address_space(1))) void*)g,
        (__attribute__((address_space(3))) void*)l, 16, 0, 0);
}

__device__ __forceinline__ int2v plswap(int a, int b) {
    return __builtin_amdgcn_permlane32_swap(a, b, false, false);
}

__device__ __forceinline__ float max3f(float a, float b, float c) {
    return fmaxf(fmaxf(a, b), c);
}

// ---------------------------------------------------------------------------
// f32 -> bf16 conversion, weights only (4 segments of 1M elements)
// ---------------------------------------------------------------------------
struct CvtSeg { const float* src; unsigned short* dst; };
struct CvtArgs { CvtSeg s[4]; };

__global__ __launch_bounds__(256)
void cvt_w(CvtArgs a)
{
    const CvtSeg seg = a.s[blockIdx.y];
    int i = blockIdx.x * 256 + threadIdx.x;          // 512 blocks x 256 = n8
    float4 x = reinterpret_cast<const float4*>(seg.src)[i*2];
    float4 y = reinterpret_cast<const float4*>(seg.src)[i*2+1];
    short8 v = short8{(short)f2bf(x.x),(short)f2bf(x.y),(short)f2bf(x.z),(short)f2bf(x.w),
                      (short)f2bf(y.x),(short)f2bf(y.y),(short)f2bf(y.z),(short)f2bf(y.w)};
    reinterpret_cast<short8*>(seg.dst)[i] = v;
}

// ---------------------------------------------------------------------------
// Projection GEMM core (r7 PROVEN BEST): A is f32 (reg-staged, converted
// in-flight, swizzled ds_write); B is bf16 (global_load_lds, inverse-swizzled
// source).  Depth-2 A-register pipeline (ar0/ar1 ping-pong, LOADA(t+2) at
// iter t); end-of-iter counted vmcnt(8) drains A(t+1)+B(t+1), leaves A(t+2)
// in flight across the barrier.  x2 unroll for static reg-set indexing.
// BM=BN=128, BK=64, 4 waves, 64KB dbuf LDS, 1 barrier/iter.
// ---------------------------------------------------------------------------
__device__ __forceinline__ void gemm_core_f32A(
    const float* __restrict__ A, const unsigned short* __restrict__ Wb,
    short* lds, int m0, int n0, int tid, f32x4 (&acc)[4][4])
{
    const int K = D_;
    const int lane = tid & 63, wave = tid >> 6;
    const int wr = wave >> 1, wc = wave & 1;
    const int r16 = lane & 15, g4 = lane >> 4;
    const int sr8  = lane >> 3;                      // 0..7 row-in-chunk
    const int slot = lane & 7;
    const int scol = ((lane ^ sr8) & 7) * 8;         // inverse-swizzled B src col
    const int wsl  = (slot ^ sr8) << 3;              // swizzled A LDS slot (shorts)

    float4 ar0[4][2], ar1[4][2];                     // two A reg sets (ping-pong)

    #define STAGEB(t, bi)                                                     \
        { _Pragma("unroll")                                                   \
          for (int c = 0; c < 4; ++c) {                                       \
              int chunk = wave*4 + c;                                         \
              gload16(Wb + (size_t)(n0 + chunk*8 + sr8) * K + (t)*64 + scol,  \
                      lds + (bi)*16384 + 8192 + chunk*512);                   \
          } }

    #define LOADA_S(t, AR)                                                    \
        { _Pragma("unroll")                                                   \
          for (int c = 0; c < 4; ++c) {                                       \
              const float* src = A + (size_t)(m0 + wave*32 + c*8 + sr8)*K     \
                                   + (t)*64 + slot*8;                         \
              AR[c][0] = *reinterpret_cast<const float4*>(src);               \
              AR[c][1] = *reinterpret_cast<const float4*>(src + 4);           \
          } }

    #define WRITEA_S(bi, AR)                                                  \
        { _Pragma("unroll")                                                   \
          for (int c = 0; c < 4; ++c) {                                       \
              unsigned w0, w1, w2, w3;                                        \
              asm("v_cvt_pk_bf16_f32 %0, %1, %2" : "=v"(w0) : "v"(AR[c][0].x), "v"(AR[c][0].y)); \
              asm("v_cvt_pk_bf16_f32 %0, %1, %2" : "=v"(w1) : "v"(AR[c][0].z), "v"(AR[c][0].w)); \
              asm("v_cvt_pk_bf16_f32 %0, %1, %2" : "=v"(w2) : "v"(AR[c][1].x), "v"(AR[c][1].y)); \
              asm("v_cvt_pk_bf16_f32 %0, %1, %2" : "=v"(w3) : "v"(AR[c][1].z), "v"(AR[c][1].w)); \
              int4v wi; wi.x = (int)w0; wi.y = (int)w1; wi.z = (int)w2; wi.w = (int)w3; \
              *reinterpret_cast<int4v*>(                                      \
                  &lds[(bi)*16384 + (wave*32 + c*8 + sr8)*64 + wsl]) = wi;    \
          } }

    const int NT = K / 64;                           // 16, even

    // prologue: B(0)+A(0) -> buf0; A(1) left in flight in ar1
    STAGEB(0, 0);
    LOADA_S(0, ar0);
    asm volatile("s_waitcnt vmcnt(0)" ::: "memory");
    WRITEA_S(0, ar0);
    LOADA_S(1, ar1);
    asm volatile("s_waitcnt lgkmcnt(0)" ::: "memory");
    __builtin_amdgcn_s_barrier();

    #define ITER(t, cur, ARCUR, AROTH)                                        \
    {                                                                         \
        if ((t) + 1 < NT) STAGEB((t)+1, (cur)^1);                             \
        if ((t) + 2 < NT) LOADA_S((t)+2, ARCUR);                              \
        const short* Ab = lds + (cur)*16384;                                  \
        const short* Bb = Ab + 8192;                                          \
        _Pragma("unroll")                                                     \
        for (int ks = 0; ks < 2; ++ks) {                                      \
            short8 af[4], bf[4];                                              \
            _Pragma("unroll")                                                 \
            for (int m = 0; m < 4; ++m) {                                     \
                int r = wr*64 + m*16 + r16;                                   \
                af[m] = *reinterpret_cast<const short8*>(                     \
                    &Ab[r*64 + (((ks*4 + g4) ^ (r16 & 7)) << 3)]);            \
            }                                                                 \
            _Pragma("unroll")                                                 \
            for (int n = 0; n < 4; ++n) {                                     \
                int r = wc*64 + n*16 + r16;                                   \
                bf[n] = *reinterpret_cast<const short8*>(                     \
                    &Bb[r*64 + (((ks*4 + g4) ^ (r16 & 7)) << 3)]);            \
            }                                                                 \
            __builtin_amdgcn_s_setprio(1);                                    \
            _Pragma("unroll")                                                 \
            for (int m = 0; m < 4; ++m)                                       \
                _Pragma("unroll")                                             \
                for (int n = 0; n < 4; ++n)                                   \
                    acc[m][n] = __builtin_amdgcn_mfma_f32_16x16x32_bf16(af[m], bf[n], acc[m][n], 0, 0, 0); \
            __builtin_amdgcn_s_setprio(0);                                    \
        }                                                                     \
        if ((t) + 1 < NT) {                                                   \
            if ((t) + 2 < NT) asm volatile("s_waitcnt vmcnt(8)" ::: "memory");\
            else              asm volatile("s_waitcnt vmcnt(0)" ::: "memory");\
            WRITEA_S((cur)^1, AROTH);                                         \
            asm volatile("s_waitcnt lgkmcnt(0)" ::: "memory");                \
        }                                                                     \
        __builtin_amdgcn_s_barrier();                                         \
    }

    for (int t = 0; t < NT; t += 2) {
        ITER(t,     0, ar0, ar1);
        ITER(t + 1, 1, ar1, ar0);
    }
    #undef ITER
    #undef STAGEB
    #undef LOADA_S
    #undef WRITEA_S
}

// ---------------------------------------------------------------------------
// bf16-A GEMM core (final GEMM): proven structure — dual gload_lds,
// counted vmcnt(8), 2 raw barriers/iter.
// ---------------------------------------------------------------------------
__device__ __forceinline__ void gemm_core_bf16A(
    const unsigned short* __restrict__ A, const unsigned short* __restrict__ Wb,
    short* lds, int m0, int n0, int tid, f32x4 (&acc)[4][4])
{
    const int K = D_;
    const int lane = tid & 63, wave = tid >> 6;
    const int wr = wave >> 1, wc = wave & 1;
    const int r16 = lane & 15, g4 = lane >> 4;
    const int srow = lane >> 3;
    const int scol = ((lane ^ srow) & 7) * 8;

    #define STAGE(t, bi)                                                      \
        { _Pragma("unroll")                                                   \
          for (int c = 0; c < 4; ++c) {                                       \
              int chunk = wave*4 + c;                                         \
              gload16(Wb + (size_t)(n0 + chunk*8 + srow) * K + (t)*64 + scol, \
                      lds + (bi)*16384 + 8192 + chunk*512);                   \
              gload16(A + (size_t)(m0 + chunk*8 + srow) * K + (t)*64 + scol,  \
                      lds + (bi)*16384 + chunk*512);                          \
          } }

    STAGE(0, 0);

    const int NT = K / 64;
    for (int t = 0; t < NT; ++t) {
        const int cur = t & 1;
        if (t + 1 < NT) {
            STAGE(t+1, cur^1);
            asm volatile("s_waitcnt vmcnt(8)" ::: "memory");
        } else {
            asm volatile("s_waitcnt vmcnt(0)" ::: "memory");
        }
        __builtin_amdgcn_s_barrier();

        const short* Ab = lds + cur*16384;
        const short* Bb = Ab + 8192;
        #pragma unroll
        for (int ks = 0; ks < 2; ++ks) {
            short8 af[4], bf[4];
            #pragma unroll
            for (int m = 0; m < 4; ++m) {
                int r = wr*64 + m*16 + r16;
                af[m] = *reinterpret_cast<const short8*>(
                    &Ab[r*64 + (((ks*4 + g4) ^ (r16 & 7)) << 3)]);
            }
            #pragma unroll
            for (int n = 0; n < 4; ++n) {
                int r = wc*64 + n*16 + r16;
                bf[n] = *reinterpret_cast<const short8*>(
                    &Bb[r*64 + (((ks*4 + g4) ^ (r16 & 7)) << 3)]);
            }
            __builtin_amdgcn_s_setprio(1);
            #pragma unroll
            for (int m = 0; m < 4; ++m)
                #pragma unroll
                for (int n = 0; n < 4; ++n)
                    acc[m][n] = __builtin_amdgcn_mfma_f32_16x16x32_bf16(af[m], bf[n], acc[m][n], 0, 0, 0);
            __builtin_amdgcn_s_setprio(0);
        }
        __builtin_amdgcn_s_barrier();
    }
    #undef STAGE
}

// Vectorized epilogue via padded LDS scratch [64][132] f32 (conflict-free),
// 2 passes of 64 rows.  MODE: 0 bf16, 1 f32, 3 bf16 scaled by CSC
template<int MODE>
__device__ __forceinline__ void epilogue_vec(
    float* Cl, void* __restrict__ Ov, int m0, int n0, int tid, f32x4 (&acc)[4][4])
{
    const int N = D_;
    const int lane = tid & 63, wave = tid >> 6;
    const int wr = wave >> 1, wc = wave & 1;
    const int r16 = lane & 15, g4 = lane >> 4;

    #pragma unroll
    for (int p = 0; p < 2; ++p) {
        if (p) __syncthreads();
        if (wr == p) {
            #pragma unroll
            for (int m = 0; m < 4; ++m)
                #pragma unroll
                for (int n = 0; n < 4; ++n)
                    #pragma unroll
                    for (int i = 0; i < 4; ++i)
                        Cl[(m*16 + g4*4 + i)*132 + wc*64 + n*16 + r16] = acc[m][n][i];
        }
        __syncthreads();
        if (MODE == 1) {
            #pragma unroll
            for (int j = 0; j < 8; ++j) {
                int c = j*256 + tid;
                int row = c >> 5, cg = c & 31;
                float4 val = *reinterpret_cast<const float4*>(&Cl[row*132 + cg*4]);
                *reinterpret_cast<float4*>(
                    &((float*)Ov)[(size_t)(m0 + p*64 + row)*N + n0 + cg*4]) = val;
            }
        } else {
            #pragma unroll
            for (int j = 0; j < 4; ++j) {
                int c2 = j*256 + tid;
                int row = c2 >> 4, col = (c2 & 15)*8;
                float4 a = *reinterpret_cast<const float4*>(&Cl[row*132 + col]);
                float4 bq = *reinterpret_cast<const float4*>(&Cl[row*132 + col + 4]);
                if (MODE == 3) {
                    a.x *= CSC; a.y *= CSC; a.z *= CSC; a.w *= CSC;
                    bq.x *= CSC; bq.y *= CSC; bq.z *= CSC; bq.w *= CSC;
                }
                short8 v = short8{(short)f2bf(a.x),(short)f2bf(a.y),(short)f2bf(a.z),(short)f2bf(a.w),
                                  (short)f2bf(bq.x),(short)f2bf(bq.y),(short)f2bf(bq.z),(short)f2bf(bq.w)};
                *reinterpret_cast<short8*>(
                    &((unsigned short*)Ov)[(size_t)(m0 + p*64 + row)*N + n0 + col]) = v;
            }
        }
    }
}

// ---------------------------------------------------------------------------
// Merged projection GEMMs: grid 1536 = 3 x 512, XCD-chunked within each 512.
// L2-reuse mapping (r6-proven): 8 temporally-adjacent blocks on an XCD share
// ONE A m-tile and sweep all 8 n-tiles; full W (2MB bf16) L2-resident.
// which: 0 = Q (bf16 out, pre-scaled CSC), 1 = K (bf16), 2 = V (transposed).
// ---------------------------------------------------------------------------
struct ProjArgs {
    const float* A[3];
    const unsigned short* W[3];
    void* O[3];
};

__global__ __launch_bounds__(256)
void gemm_proj(ProjArgs pa)
{
    __shared__ __align__(16) short lds[32768];       // 64 KB

    const int L = blockIdx.x;
    const int which = L >> 9;
    const int inner = L & 511;
    const int xcd = inner & 7, jj = inner >> 3;      // same-xcd blocks: consecutive jj
    const int m0 = (xcd*8 + (jj >> 3)) * 128;        // 8 m-tiles per XCD, held 8 blocks
    const int n0 = (jj & 7) * 128;                   // consecutive blocks sweep n
    const int tid = threadIdx.x;

    f32x4 acc[4][4] = {};
    gemm_core_f32A(pa.A[which], pa.W[which], lds, m0, n0, tid, acc);

    if (which == 2) {
        // transposed epilogue: VtG[((b*16+h)*64 + d)][s]
        const int lane = tid & 63, wave = tid >> 6;
        const int wr = wave >> 1, wc = wave & 1;
        const int r16 = lane & 15, g4 = lane >> 4;
        #pragma unroll
        for (int m = 0; m < 4; ++m) {
            int row0 = m0 + wr*64 + m*16 + g4*4;
            #pragma unroll
            for (int n = 0; n < 4; ++n) {
                int col = n0 + wc*64 + n*16 + r16;
                size_t vrow = (size_t)((row0 >> 10)*16 + (col >> 6))*64 + (col & 63);
                short4v pk = short4v{(short)f2bf(acc[m][n][0]), (short)f2bf(acc[m][n][1]),
                                     (short)f2bf(acc[m][n][2]), (short)f2bf(acc[m][n][3])};
                *reinterpret_cast<short4v*>((unsigned short*)pa.O[2] + vrow*S_ + (row0 & 1023)) = pk;
            }
        }
    } else if (which == 0) {
        epilogue_vec<3>((float*)lds, pa.O[0], m0, n0, tid, acc);
    } else {
        epilogue_vec<0>((float*)lds, pa.O[1], m0, n0, tid, acc);
    }
}

// ---------------------------------------------------------------------------
// Final GEMM (AO @ Wo.T -> f32), 512 blocks, same L2-reuse mapping.
// ---------------------------------------------------------------------------
__global__ __launch_bounds__(256)
void gemm_final(const unsigned short* __restrict__ A, const unsigned short* __restrict__ Wb,
                float* __restrict__ Ov)
{
    __shared__ __align__(16) short lds[32768];

    const int L = blockIdx.x;
    const int xcd = L & 7, jj = L >> 3;
    const int m0 = (xcd*8 + (jj >> 3)) * 128;
    const int n0 = (jj & 7) * 128;
    const int tid = threadIdx.x;

    f32x4 acc[4][4] = {};
    gemm_core_bf16A(A, Wb, lds, m0, n0, tid, acc);
    epilogue_vec<1>((float*)lds, Ov, m0, n0, tid, acc);
}

// ---------------------------------------------------------------------------
// Flash attention (causal), swapped-operand 32x32 MFMA, causal-paired tiles
// (PROVEN r0 structure, wall-clock best).  Grid 512 x 256thr, XCD-chunked:
// 16 (b,h) pairs per XCD (K+V L2-resident); block p does q-tiles {7-p, p}.
// Q pre-scaled by CSC (exp2 domain); permlane32_swap cross-half exchange.
// NEW vs r7: T5 s_setprio(1) around the PV MFMA cluster too (was QK^T-only);
// +4-7% proven on attn (m191) — PV-issuing wave preempts other waves' VALU.
// ---------------------------------------------------------------------------
__global__ __launch_bounds__(256)
void attn_fwd(const unsigned short* __restrict__ Qh,
              const unsigned short* __restrict__ Kh,
              const unsigned short* __restrict__ VtG,
              unsigned short* __restrict__ AO)
{
    __shared__ __align__(16) short Kl[2][64*64];
    __shared__ __align__(16) short Vl[2][64*64];

    const int tid  = threadIdx.x;
    const int lane = tid & 63, wave = tid >> 6;
    const int l31 = lane & 31, h32 = lane >> 5;
    const int L = blockIdx.x;
    const int xcd = L & 7, jj = L >> 3;
    const int pr = jj & 3;
    const int hb = xcd*16 + (jj >> 2);
    const int h = hb & 15, b = hb >> 4;

    const int slot = tid & 7;
    const int r0 = tid >> 3, r1 = r0 + 32;
    const int koff0 = r0*64 + ((slot ^ (r0 & 7)) << 3);
    const int koff1 = r1*64 + ((slot ^ (r1 & 7)) << 3);

    const unsigned short* Kg0 = Kh + ((size_t)b*S_)*D_ + h*HD_;
    const unsigned short* Vg0 = VtG + ((size_t)(b*H_ + h)*HD_)*S_;

    for (int t = 0; t < 2; ++t) {
        const int qb = t ? pr : (NQB - 1 - pr);
        const int q0w = qb*128 + wave*32;
        const int qi  = q0w + l31;

        short8 qf[4];
        #pragma unroll
        for (int m = 0; m < 4; ++m)
            qf[m] = *reinterpret_cast<const short8*>(
                Qh + ((size_t)b*S_ + qi)*D_ + h*HD_ + m*16 + h32*8);

        f32x16 o0 = {}, o1 = {};
        float mrow = -1e30f, lsum = 0.f;
        const int nkb = 2*qb + 2;

        short8 ka, kc, va, vc;
        ka = *reinterpret_cast<const short8*>(Kg0 + (size_t)r0*D_ + slot*8);
        kc = *reinterpret_cast<const short8*>(Kg0 + (size_t)r1*D_ + slot*8);
        va = *reinterpret_cast<const short8*>(Vg0 + (size_t)r0*S_ + slot*8);
        vc = *reinterpret_cast<const short8*>(Vg0 + (size_t)r1*S_ + slot*8);
        *reinterpret_cast<short8*>(&Kl[0][koff0]) = ka;
        *reinterpret_cast<short8*>(&Kl[0][koff1]) = kc;
        *reinterpret_cast<short8*>(&Vl[0][koff0]) = va;
        *reinterpret_cast<short8*>(&Vl[0][koff1]) = vc;
        __syncthreads();

        for (int kb = 0; kb < nkb; ++kb) {
            const int cur = kb & 1;
            const bool havenext = (kb + 1 < nkb);
            if (havenext) {
                const unsigned short* Kg = Kg0 + (size_t)(kb+1)*64*D_;
                const unsigned short* Vg = Vg0 + (kb+1)*64;
                ka = *reinterpret_cast<const short8*>(Kg + (size_t)r0*D_ + slot*8);
                kc = *reinterpret_cast<const short8*>(Kg + (size_t)r1*D_ + slot*8);
                va = *reinterpret_cast<const short8*>(Vg + (size_t)r0*S_ + slot*8);
                vc = *reinterpret_cast<const short8*>(Vg + (size_t)r1*S_ + slot*8);
            }

            if (kb*64 <= q0w + 31) {
                // === QK^T (swapped): P[k][q], already in exp2 domain ===
                f32x16 p0 = {}, p1 = {};
                __builtin_amdgcn_s_setprio(1);
                #pragma unroll
                for (int m = 0; m < 4; ++m) {
                    short8 kf0 = *reinterpret_cast<const short8*>(
                        &Kl[cur][l31*64 + ((((m<<1)|h32) ^ (l31 & 7)) << 3)]);
                    short8 kf1 = *reinterpret_cast<const short8*>(
                        &Kl[cur][(32 + l31)*64 + ((((m<<1)|h32) ^ (l31 & 7)) << 3)]);
                    p0 = __builtin_amdgcn_mfma_f32_32x32x16_bf16(kf0, qf[m], p0, 0, 0, 0);
                    p1 = __builtin_amdgcn_mfma_f32_32x32x16_bf16(kf1, qf[m], p1, 0, 0, 0);
                }
                __builtin_amdgcn_s_setprio(0);

                if (kb*64 + 63 > q0w) {
                    #pragma unroll
                    for (int r = 0; r < 16; ++r) {
                        int kk = (r & 3) + ((r >> 2) << 3) + (h32 << 2);
                        if (kb*64      + kk > qi) p0[r] = -1e30f;
                        if (kb*64 + 32 + kk > qi) p1[r] = -1e30f;
                    }
                }

                float t0 = max3f(p0[0],  p0[1],  p0[2]);
                float t1 = max3f(p0[3],  p0[4],  p0[5]);
                float t2 = max3f(p0[6],  p0[7],  p0[8]);
                float t3 = max3f(p0[9],  p0[10], p0[11]);
                float t4 = max3f(p0[12], p0[13], p0[14]);
                float t5 = max3f(p0[15], p1[0],  p1[1]);
                float t6 = max3f(p1[2],  p1[3],  p1[4]);
                float t7 = max3f(p1[5],  p1[6],  p1[7]);
                float t8 = max3f(p1[8],  p1[9],  p1[10]);
                float t9 = max3f(p1[11], p1[12], p1[13]);
                float ta = fmaxf(p1[14], p1[15]);
                float mloc = fmaxf(max3f(max3f(t0,t1,t2), max3f(t3,t4,t5), max3f(t6,t7,t8)),
                                   fmaxf(t9, ta));
                int2v mm = plswap(__float_as_int(mloc), __float_as_int(mloc));
                float pm = fmaxf(__int_as_float(mm.x), __int_as_float(mm.y));

                if (__any(pm > mrow + 11.5416f)) {
                    float mn = fmaxf(mrow, pm);
                    float so = exp2f(mrow - mn);
                    #pragma unroll
                    for (int r = 0; r < 16; ++r) { o0[r] *= so; o1[r] *= so; }
                    lsum *= so;
                    mrow = mn;
                }

                #pragma unroll
                for (int r = 0; r < 16; ++r) p0[r] = exp2f(p0[r] - mrow);
                #pragma unroll
                for (int r = 0; r < 16; ++r) p1[r] = exp2f(p1[r] - mrow);
                float sq[8];
                #pragma unroll
                for (int r = 0; r < 8; ++r)
                    sq[r] = (p0[2*r] + p0[2*r+1]) + (p1[2*r] + p1[2*r+1]);
                float rs = ((sq[0]+sq[1]) + (sq[2]+sq[3])) + ((sq[4]+sq[5]) + (sq[6]+sq[7]));
                int2v ss = plswap(__float_as_int(rs), __float_as_int(rs));
                lsum += __int_as_float(ss.x) + __int_as_float(ss.y);

                // === PV (swapped): O^T[d][q] += Vt[d][k] P[k][q] ===
                __builtin_amdgcn_s_setprio(1);
                #pragma unroll
                for (int m = 0; m < 4; ++m) {
                    const int mb = (m & 1) * 8;
                    unsigned int C0, C1, C2, C3;
                    if (m < 2) {
                        asm("v_cvt_pk_bf16_f32 %0, %1, %2" : "=v"(C0) : "v"(p0[mb+0]), "v"(p0[mb+1]));
                        asm("v_cvt_pk_bf16_f32 %0, %1, %2" : "=v"(C1) : "v"(p0[mb+2]), "v"(p0[mb+3]));
                        asm("v_cvt_pk_bf16_f32 %0, %1, %2" : "=v"(C2) : "v"(p0[mb+4]), "v"(p0[mb+5]));
                        asm("v_cvt_pk_bf16_f32 %0, %1, %2" : "=v"(C3) : "v"(p0[mb+6]), "v"(p0[mb+7]));
                    } else {
                        asm("v_cvt_pk_bf16_f32 %0, %1, %2" : "=v"(C0) : "v"(p1[mb+0]), "v"(p1[mb+1]));
                        asm("v_cvt_pk_bf16_f32 %0, %1, %2" : "=v"(C1) : "v"(p1[mb+2]), "v"(p1[mb+3]));
                        asm("v_cvt_pk_bf16_f32 %0, %1, %2" : "=v"(C2) : "v"(p1[mb+4]), "v"(p1[mb+5]));
                        asm("v_cvt_pk_bf16_f32 %0, %1, %2" : "=v"(C3) : "v"(p1[mb+6]), "v"(p1[mb+7]));
                    }
                    int2v s0 = plswap((int)C0, (int)C2);
                    int2v s1 = plswap((int)C1, (int)C3);
                    int4v wi; wi.x = s0.x; wi.y = s1.x; wi.z = s0.y; wi.w = s1.y;
                    short8 pf = __builtin_bit_cast(short8, wi);

                    short8 vf0 = *reinterpret_cast<const short8*>(
                        &Vl[cur][l31*64 + ((((m<<1)|h32) ^ (l31 & 7)) << 3)]);
                    short8 vf1 = *reinterpret_cast<const short8*>(
                        &Vl[cur][(32 + l31)*64 + ((((m<<1)|h32) ^ (l31 & 7)) << 3)]);
                    o0 = __builtin_amdgcn_mfma_f32_32x32x16_bf16(vf0, pf, o0, 0, 0, 0);
                    o1 = __builtin_amdgcn_mfma_f32_32x32x16_bf16(vf1, pf, o1, 0, 0, 0);
                }
                __builtin_amdgcn_s_setprio(0);
            }

            if (havenext) {
                const int nb = cur ^ 1;
                *reinterpret_cast<short8*>(&Kl[nb][koff0]) = ka;
                *reinterpret_cast<short8*>(&Kl[nb][koff1]) = kc;
                *reinterpret_cast<short8*>(&Vl[nb][koff0]) = va;
                *reinterpret_cast<short8*>(&Vl[nb][koff1]) = vc;
            }
            __syncthreads();
        }

        float inv = 1.f / lsum;
        #pragma unroll
        for (int tt = 0; tt < 2; ++tt) {
            #pragma unroll
            for (int g = 0; g < 4; ++g) {
                short4v pk;
                #pragma unroll
                for (int j = 0; j < 4; ++j) {
                    float val = (tt ? o1[g*4+j] : o0[g*4+j]) * inv;
                    pk[j] = (short)f2bf(val);
                }
                int d = tt*32 + g*8 + h32*4;
                *reinterpret_cast<short4v*>(AO + ((size_t)b*S_ + qi)*D_ + h*HD_ + d) = pk;
            }
        }
    }
}

// ---------------------------------------------------------------------------
extern "C" void kernel_launch(void* const* d_in, const int* in_sizes, int n_in,
                              void* d_out, int out_size, void* d_ws, size_t ws_size,
                              hipStream_t stream) {
    const float* q  = (const float*)d_in[0];
    const float* k  = (const float*)d_in[1];
    const float* v  = (const float*)d_in[2];
    const float* Wq = (const float*)d_in[3];
    const float* Wk = (const float*)d_in[4];
    const float* Wv = (const float*)d_in[5];
    const float* Wo = (const float*)d_in[6];

    unsigned short* Wqb = (unsigned short*)d_ws;            // 4 x 2MB bf16
    unsigned short* Wkb = Wqb + (size_t)D_*D_;
    unsigned short* Wvb = Wkb + (size_t)D_*D_;
    unsigned short* Wob = Wvb + (size_t)D_*D_;
    unsigned short* Qh  = Wob + (size_t)D_*D_;              // projected, bf16
    unsigned short* Kh  = Qh  + (size_t)M_*D_;
    unsigned short* VtG = Kh  + (size_t)M_*D_;              // [(b,h,d), s]
    unsigned short* AO  = VtG + (size_t)M_*D_;              // attention out

    dim3 blk(256);
    CvtArgs ca;
    ca.s[0] = CvtSeg{Wq, Wqb};
    ca.s[1] = CvtSeg{Wk, Wkb};
    ca.s[2] = CvtSeg{Wv, Wvb};
    ca.s[3] = CvtSeg{Wo, Wob};
    cvt_w<<<dim3(512, 4), blk, 0, stream>>>(ca);

    ProjArgs pa;
    pa.A[0] = q;  pa.W[0] = Wqb; pa.O[0] = Qh;
    pa.A[1] = k;  pa.W[1] = Wkb; pa.O[1] = Kh;
    pa.A[2] = v;  pa.W[2] = Wvb; pa.O[2] = VtG;
    gemm_proj<<<dim3(1536), blk, 0, stream>>>(pa);

    attn_fwd<<<dim3(512), blk, 0, stream>>>(Qh, Kh, VtG, AO);

    gemm_final<<<dim3(512), blk, 0, stream>>>(AO, Wob, (float*)d_out);
}